// Round 1
// baseline (398.979 us; speedup 1.0000x reference)
//
#include <hip/hip_runtime.h>
#include <hip/hip_bf16.h>
#include <stdint.h>

typedef __attribute__((ext_vector_type(8))) short short8;
typedef __attribute__((ext_vector_type(4))) float floatx4;
typedef __attribute__((ext_vector_type(4))) unsigned short ushortx4;

#define T_LEN 2048
#define C_DIM 1024
#define NH 16
#define HD 64

static __device__ __forceinline__ unsigned short f2bf(float f) {
  union { float f; unsigned u; } v; v.f = f;
  unsigned r = v.u + 0x7fffu + ((v.u >> 16) & 1u);
  return (unsigned short)(r >> 16);
}

static __device__ __forceinline__ void stage16(const void* g, void* l) {
  __builtin_amdgcn_global_load_lds(
      (const __attribute__((address_space(1))) void*)g,
      (__attribute__((address_space(3))) void*)l, 16, 0, 0);
}

// ---------------- cast x (f32 -> bf16), 4 elems/thread ----------------
__global__ __launch_bounds__(256) void cast_x(const float* __restrict__ in,
                                              unsigned short* __restrict__ out) {
  const long i = (long)(blockIdx.x * 256 + threadIdx.x) * 4;
  const float4 v = *(const float4*)(in + i);
  ushortx4 o;
  o[0] = f2bf(v.x); o[1] = f2bf(v.y); o[2] = f2bf(v.z); o[3] = f2bf(v.w);
  *(ushortx4*)(out + i) = o;
}

// ---------- transpose + cast: in [R][C] f32 -> out [C][R] bf16 ----------
__global__ __launch_bounds__(256) void transpose_cast(
    const float* __restrict__ in, unsigned short* __restrict__ out, int R, int C) {
  __shared__ unsigned short tile[64][72];
  const int r0 = blockIdx.y * 64;
  const int c0 = blockIdx.x * 64;
  const int tid = threadIdx.x;
#pragma unroll
  for (int e = 0; e < 4; ++e) {
    const int ch = e * 256 + tid;           // 1024 chunks of 4 floats
    const int r = ch >> 4, c4 = (ch & 15) * 4;
    const float4 v = *(const float4*)(in + (long)(r0 + r) * C + c0 + c4);
    tile[r][c4 + 0] = f2bf(v.x);
    tile[r][c4 + 1] = f2bf(v.y);
    tile[r][c4 + 2] = f2bf(v.z);
    tile[r][c4 + 3] = f2bf(v.w);
  }
  __syncthreads();
#pragma unroll
  for (int e = 0; e < 2; ++e) {
    const int ch = e * 256 + tid;           // 512 chunks of 8
    const int c = ch >> 3, k8 = (ch & 7) * 8;
    short8 w;
#pragma unroll
    for (int j = 0; j < 8; ++j) w[j] = (short)tile[k8 + j][c];
    *(short8*)(out + (long)(c0 + c) * R + r0 + k8) = w;
  }
}

// ---- V transpose (bf16): [bh][T][D] -> [bh][D][T], 64x64 tiles ----
__global__ __launch_bounds__(256) void vtrans(
    const unsigned short* __restrict__ in, unsigned short* __restrict__ out) {
  __shared__ unsigned short tile[64][72];
  const int bh = blockIdx.y;
  const int t0 = blockIdx.x * 64;
  const int tid = threadIdx.x;
  const unsigned short* src = in + (long)bh * T_LEN * HD + (long)t0 * HD;
#pragma unroll
  for (int e = 0; e < 2; ++e) {
    const int ch = e * 256 + tid;
    const int r = ch >> 3, c8 = (ch & 7) * 8;
    *(short8*)&tile[r][c8] = *(const short8*)(src + r * HD + c8);
  }
  __syncthreads();
  unsigned short* dst = out + (long)bh * HD * T_LEN + t0;
#pragma unroll
  for (int e = 0; e < 2; ++e) {
    const int ch = e * 256 + tid;
    const int d = ch >> 3, t8 = (ch & 7) * 8;
    short8 w;
#pragma unroll
    for (int j = 0; j < 8; ++j) w[j] = (short)tile[t8 + j][d];
    *(short8*)(dst + (long)d * T_LEN + t8) = w;
  }
}

// ---------------- GEMM: C = A[M,K] * Bt[N,K]^T + bias ----------------
// 128x128 tile, BK=32, 256 threads (4 waves, 2x2 of 64x64 subtiles).
// MODE 0: scatter to Q/K/V head layouts (Q scaled by 0.125), bf16 out.
// MODE 1: fp32 out row-major [M][N].
template <int MODE>
__global__ __launch_bounds__(256) void gemm_bt(
    const unsigned short* __restrict__ A,
    const unsigned short* __restrict__ Bt,
    const float* __restrict__ bias,
    int M, int N, int K,
    unsigned short* __restrict__ q_out,
    unsigned short* __restrict__ k_out,
    unsigned short* __restrict__ v_out,
    float* __restrict__ f_out) {
  __shared__ unsigned short As[128 * 32];
  __shared__ unsigned short Bs[128 * 32];
  const int tid = threadIdx.x;
  const int lane = tid & 63;
  const int wid = tid >> 6;
  const int wr = wid >> 1, wc = wid & 1;
  const int lrow = lane & 15, lgrp = lane >> 4;
  const long row0 = (long)blockIdx.y * 128;
  const long col0 = (long)blockIdx.x * 128;

  floatx4 acc[4][4];
#pragma unroll
  for (int m = 0; m < 4; ++m)
#pragma unroll
    for (int n = 0; n < 4; ++n)
      acc[m][n] = (floatx4){0.f, 0.f, 0.f, 0.f};

  const unsigned short* Abase = A + row0 * K;
  const unsigned short* Bbase = Bt + col0 * K;

  for (int k0 = 0; k0 < K; k0 += 32) {
#pragma unroll
    for (int r = 0; r < 2; ++r) {
      const int ch = r * 256 + tid;        // 16B chunk id in [0,512)
      const int trow = ch >> 2, tcol = (ch & 3) * 8;
      stage16(Abase + (long)trow * K + k0 + tcol, &As[(r * 256 + wid * 64) * 8]);
      stage16(Bbase + (long)trow * K + k0 + tcol, &Bs[(r * 256 + wid * 64) * 8]);
    }
    __syncthreads();
    short8 af[4], bf[4];
#pragma unroll
    for (int m = 0; m < 4; ++m)
      af[m] = *(const short8*)&As[(wr * 64 + m * 16 + lrow) * 32 + lgrp * 8];
#pragma unroll
    for (int n = 0; n < 4; ++n)
      bf[n] = *(const short8*)&Bs[(wc * 64 + n * 16 + lrow) * 32 + lgrp * 8];
#pragma unroll
    for (int m = 0; m < 4; ++m)
#pragma unroll
      for (int n = 0; n < 4; ++n)
        acc[m][n] = __builtin_amdgcn_mfma_f32_16x16x32_bf16(af[m], bf[n], acc[m][n], 0, 0, 0);
    __syncthreads();
  }

  if (MODE == 0) {
#pragma unroll
    for (int n = 0; n < 4; ++n) {
      const int c = (int)col0 + wc * 64 + n * 16 + lrow;
      const float bs = bias[c];
      const int sect = c >> 10;            // 0=Q 1=K 2=V
      const int h = (c & 1023) >> 6;
      const int d = c & 63;
      unsigned short* dst = sect == 0 ? q_out : (sect == 1 ? k_out : v_out);
      const float scl = sect == 0 ? 0.125f : 1.0f;  // fold 1/sqrt(64) into Q
#pragma unroll
      for (int m = 0; m < 4; ++m) {
#pragma unroll
        for (int i = 0; i < 4; ++i) {
          const long r = row0 + wr * 64 + m * 16 + lgrp * 4 + i;
          const long b = r >> 11;          // r / 2048
          const long t = r & 2047;
          const float val = (acc[m][n][i] + bs) * scl;
          dst[((b * NH + h) * T_LEN + t) * HD + d] = f2bf(val);
        }
      }
    }
  } else {
#pragma unroll
    for (int n = 0; n < 4; ++n) {
      const int c = (int)col0 + wc * 64 + n * 16 + lrow;
      const float bs = bias[c];
#pragma unroll
      for (int m = 0; m < 4; ++m) {
#pragma unroll
        for (int i = 0; i < 4; ++i) {
          const long r = row0 + wr * 64 + m * 16 + lgrp * 4 + i;
          f_out[r * (long)N + c] = acc[m][n][i] + bs;
        }
      }
    }
  }
}

// ---------------- flash attention: 1 wave per 16 q-rows ----------------
// Q pre-scaled by 1/8. K [bh][T][D], Vt [bh][D][T]. Out attn [B][T][C] bf16.
__global__ __launch_bounds__(64) void attn_fwd(
    const unsigned short* __restrict__ Qb,
    const unsigned short* __restrict__ Kb,
    const unsigned short* __restrict__ Vt,
    unsigned short* __restrict__ attn) {
  __shared__ unsigned short p_lds[16][40];   // padded: 40 halfwords/row
  const int bh = blockIdx.y;
  const int q0 = blockIdx.x * 16;
  const int b = bh >> 4, h = bh & 15;
  const int lane = threadIdx.x;
  const int lrow = lane & 15, lgrp = lane >> 4;

  const unsigned short* Qh = Qb + (long)bh * T_LEN * HD;
  const unsigned short* Kh = Kb + (long)bh * T_LEN * HD;
  const unsigned short* Vh = Vt + (long)bh * HD * T_LEN;

  short8 aq[2];
#pragma unroll
  for (int kk = 0; kk < 2; ++kk)
    aq[kk] = *(const short8*)(Qh + (long)(q0 + lrow) * HD + kk * 32 + lgrp * 8);

  float m_i[4], s_i[4];
  floatx4 o[4];
#pragma unroll
  for (int i = 0; i < 4; ++i) { m_i[i] = -1e30f; s_i[i] = 0.f; }
#pragma unroll
  for (int d0 = 0; d0 < 4; ++d0) o[d0] = (floatx4){0.f, 0.f, 0.f, 0.f};

  const int send = q0 + 16;                  // causal extent (exclusive)
  for (int s0 = 0; s0 < send; s0 += 32) {
    floatx4 sf[2];
    sf[0] = (floatx4){0.f, 0.f, 0.f, 0.f};
    sf[1] = (floatx4){0.f, 0.f, 0.f, 0.f};
#pragma unroll
    for (int sc = 0; sc < 2; ++sc) {
#pragma unroll
      for (int kk = 0; kk < 2; ++kk) {
        short8 kf = *(const short8*)(Kh + (long)(s0 + sc * 16 + lrow) * HD + kk * 32 + lgrp * 8);
        sf[sc] = __builtin_amdgcn_mfma_f32_16x16x32_bf16(aq[kk], kf, sf[sc], 0, 0, 0);
      }
    }
    // causal mask: element (row q0+lgrp*4+i, col s0+sc*16+lrow)
#pragma unroll
    for (int sc = 0; sc < 2; ++sc) {
      const int s = s0 + sc * 16 + lrow;
#pragma unroll
      for (int i = 0; i < 4; ++i) {
        const int q = q0 + lgrp * 4 + i;
        if (s > q) sf[sc][i] = -1e30f;
      }
    }
    // online softmax (row spread across 16 lanes of same lgrp)
    float p[2][4];
#pragma unroll
    for (int i = 0; i < 4; ++i) {
      float pm = fmaxf(sf[0][i], sf[1][i]);
#pragma unroll
      for (int off = 1; off < 16; off <<= 1)
        pm = fmaxf(pm, __shfl_xor(pm, off, 16));
      const float mnew = fmaxf(m_i[i], pm);
      const float scale = __expf(m_i[i] - mnew);
      float rsum = 0.f;
#pragma unroll
      for (int sc = 0; sc < 2; ++sc) {
        const float pv = __expf(sf[sc][i] - mnew);
        p[sc][i] = pv;
        rsum += pv;
      }
#pragma unroll
      for (int off = 1; off < 16; off <<= 1)
        rsum += __shfl_xor(rsum, off, 16);
      m_i[i] = mnew;
      s_i[i] = s_i[i] * scale + rsum;
#pragma unroll
      for (int d0 = 0; d0 < 4; ++d0) o[d0][i] *= scale;
    }
    // P (D-layout) -> LDS -> A-operand layout
#pragma unroll
    for (int sc = 0; sc < 2; ++sc)
#pragma unroll
      for (int i = 0; i < 4; ++i)
        p_lds[lgrp * 4 + i][sc * 16 + lrow] = f2bf(p[sc][i]);
    __syncthreads();
    short8 pf = *(const short8*)&p_lds[lrow][lgrp * 8];
#pragma unroll
    for (int d0 = 0; d0 < 4; ++d0) {
      short8 vf = *(const short8*)(Vh + (long)(d0 * 16 + lrow) * T_LEN + s0 + lgrp * 8);
      o[d0] = __builtin_amdgcn_mfma_f32_16x16x32_bf16(pf, vf, o[d0], 0, 0, 0);
    }
    __syncthreads();
  }
#pragma unroll
  for (int d0 = 0; d0 < 4; ++d0) {
#pragma unroll
    for (int i = 0; i < 4; ++i) {
      const int q = q0 + lgrp * 4 + i;
      const float val = o[d0][i] / s_i[i];
      attn[(long)(b * T_LEN + q) * C_DIM + h * HD + d0 * 16 + lrow] = f2bf(val);
    }
  }
}

extern "C" void kernel_launch(void* const* d_in, const int* in_sizes, int n_in,
                              void* d_out, int out_size, void* d_ws, size_t ws_size,
                              hipStream_t stream) {
  const float* x     = (const float*)d_in[0];
  const float* Wqkv  = (const float*)d_in[1];
  const float* bqkv  = (const float*)d_in[2];
  const float* Wproj = (const float*)d_in[3];
  const float* bproj = (const float*)d_in[4];
  float* out = (float*)d_out;
  char* ws = (char*)d_ws;
  const size_t MB = 1024 * 1024;
  unsigned short* Qb     = (unsigned short*)(ws + 0 * MB);   // [B,N,T,D] bf16, pre-scaled 1/8
  unsigned short* Kb     = (unsigned short*)(ws + 8 * MB);   // [B,N,T,D]
  unsigned short* Vb     = (unsigned short*)(ws + 16 * MB);  // [B,N,T,D]
  unsigned short* Vt     = (unsigned short*)(ws + 24 * MB);  // [B,N,D,T]
  unsigned short* attn   = (unsigned short*)(ws + 32 * MB);  // [B,T,C]
  unsigned short* xbf    = (unsigned short*)(ws + 40 * MB);  // [B*T,C]
  unsigned short* Wqkvt  = (unsigned short*)(ws + 48 * MB);  // [3C,C]
  unsigned short* Wprojt = (unsigned short*)(ws + 54 * MB);  // [C,C]

  cast_x<<<4096, 256, 0, stream>>>(x, xbf);
  transpose_cast<<<dim3(48, 16), 256, 0, stream>>>(Wqkv, Wqkvt, 1024, 3072);
  transpose_cast<<<dim3(16, 16), 256, 0, stream>>>(Wproj, Wprojt, 1024, 1024);
  gemm_bt<0><<<dim3(24, 32), 256, 0, stream>>>(xbf, Wqkvt, bqkv, 4096, 3072, 1024,
                                               Qb, Kb, Vb, nullptr);
  vtrans<<<dim3(32, 32), 256, 0, stream>>>(Vb, Vt);
  attn_fwd<<<dim3(128, 32), 64, 0, stream>>>(Qb, Kb, Vt, attn);
  gemm_bt<1><<<dim3(8, 32), 256, 0, stream>>>(attn, Wprojt, bproj, 4096, 1024, 1024,
                                              nullptr, nullptr, nullptr, out);
}

// Round 2
// 347.795 us; speedup vs baseline: 1.1472x; 1.1472x over previous
//
#include <hip/hip_runtime.h>
#include <hip/hip_bf16.h>
#include <stdint.h>

typedef __attribute__((ext_vector_type(8))) short short8;
typedef __attribute__((ext_vector_type(4))) float floatx4;
typedef __attribute__((ext_vector_type(4))) unsigned short ushortx4;

#define T_LEN 2048
#define C_DIM 1024
#define NH 16
#define HD 64

static __device__ __forceinline__ unsigned short f2bf(float f) {
  union { float f; unsigned u; } v; v.f = f;
  unsigned r = v.u + 0x7fffu + ((v.u >> 16) & 1u);
  return (unsigned short)(r >> 16);
}

static __device__ __forceinline__ void stage16(const void* g, void* l) {
  __builtin_amdgcn_global_load_lds(
      (const __attribute__((address_space(1))) void*)g,
      (__attribute__((address_space(3))) void*)l, 16, 0, 0);
}

// ---------------- cast x (f32 -> bf16), 4 elems/thread ----------------
__global__ __launch_bounds__(256) void cast_x(const float* __restrict__ in,
                                              unsigned short* __restrict__ out) {
  const long i = (long)(blockIdx.x * 256 + threadIdx.x) * 4;
  const float4 v = *(const float4*)(in + i);
  ushortx4 o;
  o[0] = f2bf(v.x); o[1] = f2bf(v.y); o[2] = f2bf(v.z); o[3] = f2bf(v.w);
  *(ushortx4*)(out + i) = o;
}

// ---------- transpose + cast: in [R][C] f32 -> out [C][R] bf16 ----------
__global__ __launch_bounds__(256) void transpose_cast(
    const float* __restrict__ in, unsigned short* __restrict__ out, int R, int C) {
  __shared__ unsigned short tile[64][72];
  const int r0 = blockIdx.y * 64;
  const int c0 = blockIdx.x * 64;
  const int tid = threadIdx.x;
#pragma unroll
  for (int e = 0; e < 4; ++e) {
    const int ch = e * 256 + tid;           // 1024 chunks of 4 floats
    const int r = ch >> 4, c4 = (ch & 15) * 4;
    const float4 v = *(const float4*)(in + (long)(r0 + r) * C + c0 + c4);
    tile[r][c4 + 0] = f2bf(v.x);
    tile[r][c4 + 1] = f2bf(v.y);
    tile[r][c4 + 2] = f2bf(v.z);
    tile[r][c4 + 3] = f2bf(v.w);
  }
  __syncthreads();
#pragma unroll
  for (int e = 0; e < 2; ++e) {
    const int ch = e * 256 + tid;           // 512 chunks of 8
    const int c = ch >> 3, k8 = (ch & 7) * 8;
    short8 w;
#pragma unroll
    for (int j = 0; j < 8; ++j) w[j] = (short)tile[k8 + j][c];
    *(short8*)(out + (long)(c0 + c) * R + r0 + k8) = w;
  }
}

// ---- V transpose (bf16): [bh][T][D] -> [bh][D][T], 64x64 tiles ----
__global__ __launch_bounds__(256) void vtrans(
    const unsigned short* __restrict__ in, unsigned short* __restrict__ out) {
  __shared__ unsigned short tile[64][72];
  const int bh = blockIdx.y;
  const int t0 = blockIdx.x * 64;
  const int tid = threadIdx.x;
  const unsigned short* src = in + (long)bh * T_LEN * HD + (long)t0 * HD;
#pragma unroll
  for (int e = 0; e < 2; ++e) {
    const int ch = e * 256 + tid;
    const int r = ch >> 3, c8 = (ch & 7) * 8;
    *(short8*)&tile[r][c8] = *(const short8*)(src + r * HD + c8);
  }
  __syncthreads();
  unsigned short* dst = out + (long)bh * HD * T_LEN + t0;
#pragma unroll
  for (int e = 0; e < 2; ++e) {
    const int ch = e * 256 + tid;
    const int d = ch >> 3, t8 = (ch & 7) * 8;
    short8 w;
#pragma unroll
    for (int j = 0; j < 8; ++j) w[j] = (short)tile[t8 + j][d];
    *(short8*)(dst + (long)d * T_LEN + t8) = w;
  }
}

// ---------------- GEMM: C = A[M,K] * Bt[N,K]^T + bias ----------------
// 128x128 tile, BK=32, 256 threads (4 waves, 2x2 of 64x64 subtiles).
// MODE 0: scatter to Q/K/V head layouts (Q scaled by 0.125), bf16 out.
// MODE 1: fp32 out row-major [M][N].
template <int MODE>
__global__ __launch_bounds__(256) void gemm_bt(
    const unsigned short* __restrict__ A,
    const unsigned short* __restrict__ Bt,
    const float* __restrict__ bias,
    int M, int N, int K,
    unsigned short* __restrict__ q_out,
    unsigned short* __restrict__ k_out,
    unsigned short* __restrict__ v_out,
    float* __restrict__ f_out) {
  __shared__ unsigned short As[128 * 32];
  __shared__ unsigned short Bs[128 * 32];
  const int tid = threadIdx.x;
  const int lane = tid & 63;
  const int wid = tid >> 6;
  const int wr = wid >> 1, wc = wid & 1;
  const int lrow = lane & 15, lgrp = lane >> 4;
  const long row0 = (long)blockIdx.y * 128;
  const long col0 = (long)blockIdx.x * 128;

  floatx4 acc[4][4];
#pragma unroll
  for (int m = 0; m < 4; ++m)
#pragma unroll
    for (int n = 0; n < 4; ++n)
      acc[m][n] = (floatx4){0.f, 0.f, 0.f, 0.f};

  const unsigned short* Abase = A + row0 * K;
  const unsigned short* Bbase = Bt + col0 * K;

  for (int k0 = 0; k0 < K; k0 += 32) {
#pragma unroll
    for (int r = 0; r < 2; ++r) {
      const int ch = r * 256 + tid;        // 16B chunk id in [0,512)
      const int trow = ch >> 2, tcol = (ch & 3) * 8;
      stage16(Abase + (long)trow * K + k0 + tcol, &As[(r * 256 + wid * 64) * 8]);
      stage16(Bbase + (long)trow * K + k0 + tcol, &Bs[(r * 256 + wid * 64) * 8]);
    }
    __syncthreads();
    short8 af[4], bf[4];
#pragma unroll
    for (int m = 0; m < 4; ++m)
      af[m] = *(const short8*)&As[(wr * 64 + m * 16 + lrow) * 32 + lgrp * 8];
#pragma unroll
    for (int n = 0; n < 4; ++n)
      bf[n] = *(const short8*)&Bs[(wc * 64 + n * 16 + lrow) * 32 + lgrp * 8];
#pragma unroll
    for (int m = 0; m < 4; ++m)
#pragma unroll
      for (int n = 0; n < 4; ++n)
        acc[m][n] = __builtin_amdgcn_mfma_f32_16x16x32_bf16(af[m], bf[n], acc[m][n], 0, 0, 0);
    __syncthreads();
  }

  if (MODE == 0) {
#pragma unroll
    for (int n = 0; n < 4; ++n) {
      const int c = (int)col0 + wc * 64 + n * 16 + lrow;
      const float bs = bias[c];
      const int sect = c >> 10;            // 0=Q 1=K 2=V
      const int h = (c & 1023) >> 6;
      const int d = c & 63;
      unsigned short* dst = sect == 0 ? q_out : (sect == 1 ? k_out : v_out);
      const float scl = sect == 0 ? 0.125f : 1.0f;  // fold 1/sqrt(64) into Q
#pragma unroll
      for (int m = 0; m < 4; ++m) {
#pragma unroll
        for (int i = 0; i < 4; ++i) {
          const long r = row0 + wr * 64 + m * 16 + lgrp * 4 + i;
          const long b = r >> 11;          // r / 2048
          const long t = r & 2047;
          const float val = (acc[m][n][i] + bs) * scl;
          dst[((b * NH + h) * T_LEN + t) * HD + d] = f2bf(val);
        }
      }
    }
  } else {
#pragma unroll
    for (int n = 0; n < 4; ++n) {
      const int c = (int)col0 + wc * 64 + n * 16 + lrow;
      const float bs = bias[c];
#pragma unroll
      for (int m = 0; m < 4; ++m) {
#pragma unroll
        for (int i = 0; i < 4; ++i) {
          const long r = row0 + wr * 64 + m * 16 + lgrp * 4 + i;
          f_out[r * (long)N + c] = acc[m][n][i] + bs;
        }
      }
    }
  }
}

// ---------------- flash attention v2: 4 waves/block, 32 q-rows/wave ----------------
// Q pre-scaled by 1/8. K [bh][T][D], Vt [bh][D][T]. Out attn [B][T][C] bf16.
// Each wave independent: 32 q rows (2 x 16), KV step = 64 (4 x 16).
// No __syncthreads (divergent trip counts per wave) — per-wave LDS slices.
__global__ __launch_bounds__(256) void attn_fwd(
    const unsigned short* __restrict__ Qb,
    const unsigned short* __restrict__ Kb,
    const unsigned short* __restrict__ Vt,
    unsigned short* __restrict__ attn) {
  __shared__ unsigned short p_lds[4][32][72];   // per-wave [q32][s64] pad->72
  const int bh = blockIdx.y;
  const int qt = (int)(gridDim.x - 1 - blockIdx.x);  // reversed: long blocks first
  const int b = bh >> 4, h = bh & 15;
  const int wid = (int)threadIdx.x >> 6;
  const int lane = (int)threadIdx.x & 63;
  const int lrow = lane & 15, lgrp = lane >> 4;
  const int q0 = qt * 128 + wid * 32;           // this wave's first q row

  const unsigned short* Qh = Qb + (long)bh * T_LEN * HD;
  const unsigned short* Kh = Kb + (long)bh * T_LEN * HD;
  const unsigned short* Vh = Vt + (long)bh * HD * T_LEN;

  // Q fragments: [qsub][kk]
  short8 aq[2][2];
#pragma unroll
  for (int qs = 0; qs < 2; ++qs)
#pragma unroll
    for (int kk = 0; kk < 2; ++kk)
      aq[qs][kk] = *(const short8*)(Qh + (long)(q0 + qs * 16 + lrow) * HD + kk * 32 + lgrp * 8);

  float m_i[2][4], s_i[2][4];
  floatx4 o[2][4];                              // [qsub][d0]
#pragma unroll
  for (int qs = 0; qs < 2; ++qs)
#pragma unroll
    for (int i = 0; i < 4; ++i) { m_i[qs][i] = -1e30f; s_i[qs][i] = 0.f; }
#pragma unroll
  for (int qs = 0; qs < 2; ++qs)
#pragma unroll
    for (int d0 = 0; d0 < 4; ++d0) o[qs][d0] = (floatx4){0.f, 0.f, 0.f, 0.f};

  const int send = q0 + 32;                     // causal extent (exclusive)
  for (int s0 = 0; s0 < send; s0 += 64) {
    // ---- QK^T: S[2x16 q][4x16 s] ----
    floatx4 sf[2][4];
#pragma unroll
    for (int qs = 0; qs < 2; ++qs)
#pragma unroll
      for (int sc = 0; sc < 4; ++sc) sf[qs][sc] = (floatx4){0.f, 0.f, 0.f, 0.f};
#pragma unroll
    for (int sc = 0; sc < 4; ++sc) {
#pragma unroll
      for (int kk = 0; kk < 2; ++kk) {
        const short8 kf = *(const short8*)(Kh + (long)(s0 + sc * 16 + lrow) * HD + kk * 32 + lgrp * 8);
#pragma unroll
        for (int qs = 0; qs < 2; ++qs)
          sf[qs][sc] = __builtin_amdgcn_mfma_f32_16x16x32_bf16(aq[qs][kk], kf, sf[qs][sc], 0, 0, 0);
      }
    }
    // ---- causal mask (only near diagonal) ----
    if (s0 + 64 > q0) {
#pragma unroll
      for (int qs = 0; qs < 2; ++qs) {
#pragma unroll
        for (int sc = 0; sc < 4; ++sc) {
          const int s = s0 + sc * 16 + lrow;
#pragma unroll
          for (int i = 0; i < 4; ++i) {
            const int q = q0 + qs * 16 + lgrp * 4 + i;
            if (s > q) sf[qs][sc][i] = -1e30f;
          }
        }
      }
    }
    // ---- online softmax (row = fixed q, spread over 16 lanes x 4 sc) ----
#pragma unroll
    for (int qs = 0; qs < 2; ++qs) {
#pragma unroll
      for (int i = 0; i < 4; ++i) {
        float pm = fmaxf(fmaxf(sf[qs][0][i], sf[qs][1][i]), fmaxf(sf[qs][2][i], sf[qs][3][i]));
#pragma unroll
        for (int off = 1; off < 16; off <<= 1)
          pm = fmaxf(pm, __shfl_xor(pm, off, 16));
        const float mnew = fmaxf(m_i[qs][i], pm);
        const float scale = __expf(m_i[qs][i] - mnew);
        float rsum = 0.f;
#pragma unroll
        for (int sc = 0; sc < 4; ++sc) {
          const float pv = __expf(sf[qs][sc][i] - mnew);
          sf[qs][sc][i] = pv;
          rsum += pv;
        }
#pragma unroll
        for (int off = 1; off < 16; off <<= 1)
          rsum += __shfl_xor(rsum, off, 16);
        m_i[qs][i] = mnew;
        s_i[qs][i] = s_i[qs][i] * scale + rsum;
#pragma unroll
        for (int d0 = 0; d0 < 4; ++d0) o[qs][d0][i] *= scale;
      }
    }
    // ---- P (D-layout) -> LDS -> A-operand layout ----
#pragma unroll
    for (int qs = 0; qs < 2; ++qs)
#pragma unroll
      for (int sc = 0; sc < 4; ++sc)
#pragma unroll
        for (int i = 0; i < 4; ++i)
          p_lds[wid][qs * 16 + lgrp * 4 + i][sc * 16 + lrow] = f2bf(sf[qs][sc][i]);
    short8 pf[2][2];
#pragma unroll
    for (int qs = 0; qs < 2; ++qs)
#pragma unroll
      for (int sh = 0; sh < 2; ++sh)
        pf[qs][sh] = *(const short8*)&p_lds[wid][qs * 16 + lrow][sh * 32 + lgrp * 8];
    // ---- PV: O[2x16 q][4x16 d] += P * V^T-rows ----
#pragma unroll
    for (int d0 = 0; d0 < 4; ++d0) {
#pragma unroll
      for (int sh = 0; sh < 2; ++sh) {
        const short8 vf = *(const short8*)(Vh + (long)(d0 * 16 + lrow) * T_LEN + s0 + sh * 32 + lgrp * 8);
#pragma unroll
        for (int qs = 0; qs < 2; ++qs)
          o[qs][d0] = __builtin_amdgcn_mfma_f32_16x16x32_bf16(pf[qs][sh], vf, o[qs][d0], 0, 0, 0);
      }
    }
  }
  // ---- epilogue ----
#pragma unroll
  for (int qs = 0; qs < 2; ++qs) {
#pragma unroll
    for (int d0 = 0; d0 < 4; ++d0) {
#pragma unroll
      for (int i = 0; i < 4; ++i) {
        const int q = q0 + qs * 16 + lgrp * 4 + i;
        const float val = o[qs][d0][i] / s_i[qs][i];
        attn[(long)(b * T_LEN + q) * C_DIM + h * HD + d0 * 16 + lrow] = f2bf(val);
      }
    }
  }
}

extern "C" void kernel_launch(void* const* d_in, const int* in_sizes, int n_in,
                              void* d_out, int out_size, void* d_ws, size_t ws_size,
                              hipStream_t stream) {
  const float* x     = (const float*)d_in[0];
  const float* Wqkv  = (const float*)d_in[1];
  const float* bqkv  = (const float*)d_in[2];
  const float* Wproj = (const float*)d_in[3];
  const float* bproj = (const float*)d_in[4];
  float* out = (float*)d_out;
  char* ws = (char*)d_ws;
  const size_t MB = 1024 * 1024;
  unsigned short* Qb     = (unsigned short*)(ws + 0 * MB);   // [B,N,T,D] bf16, pre-scaled 1/8
  unsigned short* Kb     = (unsigned short*)(ws + 8 * MB);   // [B,N,T,D]
  unsigned short* Vb     = (unsigned short*)(ws + 16 * MB);  // [B,N,T,D]
  unsigned short* Vt     = (unsigned short*)(ws + 24 * MB);  // [B,N,D,T]
  unsigned short* attn   = (unsigned short*)(ws + 32 * MB);  // [B,T,C]
  unsigned short* xbf    = (unsigned short*)(ws + 40 * MB);  // [B*T,C]
  unsigned short* Wqkvt  = (unsigned short*)(ws + 48 * MB);  // [3C,C]
  unsigned short* Wprojt = (unsigned short*)(ws + 54 * MB);  // [C,C]

  cast_x<<<4096, 256, 0, stream>>>(x, xbf);
  transpose_cast<<<dim3(48, 16), 256, 0, stream>>>(Wqkv, Wqkvt, 1024, 3072);
  transpose_cast<<<dim3(16, 16), 256, 0, stream>>>(Wproj, Wprojt, 1024, 1024);
  gemm_bt<0><<<dim3(24, 32), 256, 0, stream>>>(xbf, Wqkvt, bqkv, 4096, 3072, 1024,
                                               Qb, Kb, Vb, nullptr);
  vtrans<<<dim3(32, 32), 256, 0, stream>>>(Vb, Vt);
  attn_fwd<<<dim3(16, 32), 256, 0, stream>>>(Qb, Kb, Vt, attn);
  gemm_bt<1><<<dim3(8, 32), 256, 0, stream>>>(attn, Wprojt, bproj, 4096, 1024, 1024,
                                              nullptr, nullptr, nullptr, out);
}